// Round 1
// baseline (1910.365 us; speedup 1.0000x reference)
//
#include <hip/hip_runtime.h>

#define B_DIM 32
#define T_DIM 2048
#define D_DIM 512
#define V_DIM 5
#define L_DIM 256
#define S_MAX 513            // 2*L+1
#define NEG (-1e9f)

__device__ __forceinline__ float lae(float a, float b) {
    float m = fmaxf(a, b);
    float n = fminf(a, b);
    return m + log1pf(__expf(n - m));
}

// Kernel 1: logits = hs @ W + b, log_softmax over V, probs. Thread-per-row.
// W/b accessed with wave-uniform indices -> compiler emits scalar loads.
__global__ __launch_bounds__(256) void k_logits_softmax(
    const float* __restrict__ hs, const float* __restrict__ W,
    const float* __restrict__ bias, float* __restrict__ logp,
    float* __restrict__ probs)
{
    int r = blockIdx.x * blockDim.x + threadIdx.x;   // row in [0, B*T)
    const float* x = hs + (size_t)r * D_DIM;

    float acc[V_DIM];
#pragma unroll
    for (int v = 0; v < V_DIM; ++v) acc[v] = bias[v];

    for (int k = 0; k < D_DIM; k += 8) {
        float4 xa = *reinterpret_cast<const float4*>(x + k);
        float4 xb = *reinterpret_cast<const float4*>(x + k + 4);
        const float xs[8] = {xa.x, xa.y, xa.z, xa.w, xb.x, xb.y, xb.z, xb.w};
#pragma unroll
        for (int j = 0; j < 8; ++j) {
#pragma unroll
            for (int v = 0; v < V_DIM; ++v)
                acc[v] = fmaf(xs[j], W[(k + j) * V_DIM + v], acc[v]);
        }
    }

    float m = fmaxf(fmaxf(fmaxf(acc[0], acc[1]), fmaxf(acc[2], acc[3])), acc[4]);
    float e[V_DIM];
    float s = 0.f;
#pragma unroll
    for (int v = 0; v < V_DIM; ++v) { e[v] = __expf(acc[v] - m); s += e[v]; }
    float lse = m + __logf(s);
    float inv = 1.f / s;

    size_t base = (size_t)r * V_DIM;
#pragma unroll
    for (int v = 0; v < V_DIM; ++v) {
        logp[base + v]  = acc[v] - lse;
        probs[base + v] = e[v] * inv;
    }
}

// Kernel 2: CTC forward scan. One block per sample, thread s = state s.
// alpha double-buffered in LDS, ONE barrier per time step.
__global__ __launch_bounds__(576) void k_ctc(
    const float* __restrict__ logp, const int* __restrict__ ys_pad,
    const int* __restrict__ hlens, const int* __restrict__ ys_lens,
    float* __restrict__ nll_out)
{
    __shared__ float alpha[2][S_MAX];
    __shared__ float lps[2][V_DIM];

    const int b   = blockIdx.x;
    const int tid = threadIdx.x;
    const int lb  = ys_lens[b];
    const int Sb  = 2 * lb + 1;
    const int hlen = hlens[b];
    const float* lp = logp + (size_t)b * T_DIM * V_DIM;

    // per-thread extended symbol + skip-transition flag
    int sym = 0;           // blank
    bool skip = false;
    if ((tid & 1) && tid < Sb) {
        int j = tid >> 1;
        sym = ys_pad[b * L_DIM + j];
        if (tid >= 3) skip = (sym != ys_pad[b * L_DIM + j - 1]);
    }

    if (tid < S_MAX) alpha[0][tid] = NEG;
    if (tid < V_DIM) {
        lps[0][tid] = lp[tid];          // t = 0
        lps[1][tid] = lp[V_DIM + tid];  // t = 1 (T_DIM >= 2 always)
    }
    __syncthreads();
    if (tid == 0) alpha[0][0] = lps[0][0];
    else if (tid == 1) alpha[0][1] = lps[0][sym];
    __syncthreads();

    int cur = 0;
    for (int t = 1; t < hlen; ++t) {
        const int nxt = cur ^ 1;
        const bool active = (tid < Sb);
        float nv;
        if (active) {
            float a0 = alpha[cur][tid];
            float a1 = (tid >= 1) ? alpha[cur][tid - 1] : NEG;
            float a2 = skip ? alpha[cur][tid - 2] : NEG;
            nv = lae(lae(a0, a1), a2) + lps[t & 1][sym];
        }
        // prefetch lp for t+1 into the other lp buffer (parity (t+1)&1)
        if (tid < V_DIM && (t + 1) < hlen)
            lps[(t + 1) & 1][tid] = lp[(size_t)(t + 1) * V_DIM + tid];
        if (active) alpha[nxt][tid] = nv;
        __syncthreads();
        cur = nxt;
    }

    if (tid == 0) {
        float v = -lae(alpha[cur][2 * lb - 1], alpha[cur][2 * lb]);
        if (v > 1e8f) v = 0.f;   // zero_infinity
        nll_out[b] = v;
    }
}

// Kernel 3: deterministic reduction of 32 per-sample NLLs -> loss.
__global__ __launch_bounds__(64) void k_finalize(
    const float* __restrict__ nll, float* __restrict__ out)
{
    int tid = threadIdx.x;
    float v = (tid < B_DIM) ? nll[tid] : 0.f;
#pragma unroll
    for (int off = 32; off; off >>= 1) v += __shfl_down(v, off, 64);
    if (tid == 0) out[0] = v / (float)B_DIM;
}

extern "C" void kernel_launch(void* const* d_in, const int* in_sizes, int n_in,
                              void* d_out, int out_size, void* d_ws, size_t ws_size,
                              hipStream_t stream) {
    const float* hs      = (const float*)d_in[0];
    const float* W       = (const float*)d_in[1];
    const float* bias    = (const float*)d_in[2];
    const int*   hlens   = (const int*)d_in[3];
    const int*   ys_pad  = (const int*)d_in[4];
    const int*   ys_lens = (const int*)d_in[5];

    float* out   = (float*)d_out;
    float* logp  = out + 1;                                      // (B,T,V) log-softmax
    float* probs = out + 1 + (size_t)B_DIM * T_DIM * V_DIM;      // (B,T,V) softmax
    float* nll   = (float*)d_ws;                                 // 32 floats

    hipLaunchKernelGGL(k_logits_softmax, dim3(B_DIM * T_DIM / 256), dim3(256), 0, stream,
                       hs, W, bias, logp, probs);
    hipLaunchKernelGGL(k_ctc, dim3(B_DIM), dim3(576), 0, stream,
                       logp, ys_pad, hlens, ys_lens, nll);
    hipLaunchKernelGGL(k_finalize, dim3(1), dim3(64), 0, stream, nll, out);
}

// Round 3
// 492.652 us; speedup vs baseline: 3.8777x; 3.8777x over previous
//
#include <hip/hip_runtime.h>
#include <math.h>

#define B_DIM 32
#define T_DIM 2048
#define D_DIM 512
#define V_DIM 5
#define L_DIM 256
#define LN2D 0.6931471805599453

// Kernel 1: logits = hs @ W + b, log_softmax over V, probs. Thread-per-row.
__global__ __launch_bounds__(256) void k_logits_softmax(
    const float* __restrict__ hs, const float* __restrict__ W,
    const float* __restrict__ bias, float* __restrict__ logp,
    float* __restrict__ probs)
{
    int r = blockIdx.x * blockDim.x + threadIdx.x;   // row in [0, B*T)
    const float* x = hs + (size_t)r * D_DIM;

    float acc[V_DIM];
#pragma unroll
    for (int v = 0; v < V_DIM; ++v) acc[v] = bias[v];

    for (int k = 0; k < D_DIM; k += 8) {
        float4 xa = *reinterpret_cast<const float4*>(x + k);
        float4 xb = *reinterpret_cast<const float4*>(x + k + 4);
        const float xs[8] = {xa.x, xa.y, xa.z, xa.w, xb.x, xb.y, xb.z, xb.w};
#pragma unroll
        for (int j = 0; j < 8; ++j) {
#pragma unroll
            for (int v = 0; v < V_DIM; ++v)
                acc[v] = fmaf(xs[j], W[(k + j) * V_DIM + v], acc[v]);
        }
    }

    float m = fmaxf(fmaxf(fmaxf(acc[0], acc[1]), fmaxf(acc[2], acc[3])), acc[4]);
    float e[V_DIM];
    float s = 0.f;
#pragma unroll
    for (int v = 0; v < V_DIM; ++v) { e[v] = __expf(acc[v] - m); s += e[v]; }
    float lse = m + __logf(s);
    float inv = 1.f / s;

    size_t base = (size_t)r * V_DIM;
#pragma unroll
    for (int v = 0; v < V_DIM; ++v) {
        logp[base + v]  = acc[v] - lse;
        probs[base + v] = e[v] * inv;
    }
}

// Kernel 2: CTC forward scan, linear-probability domain in DOUBLE with exact
// pow2 rescaling every 8 steps. One wave per sample, 8 states/lane (+1 ghost)
// in registers. No barriers/LDS in the hot loop; neighbor exchange via one
// __shfl_up per step. Double is required: within-vector dynamic range of
// alpha reaches ~2^350 below the max (path-count gap between the running max
// state and the on-track states) which exceeds float range and flushed the
// readout mass to zero (round-2 failure, loss error 40).
__global__ __launch_bounds__(64) void k_ctc(
    const float* __restrict__ probs, const int* __restrict__ ys_pad,
    const int* __restrict__ hlens, const int* __restrict__ ys_lens,
    float* __restrict__ nll_out)
{
    __shared__ double s_alpha[513];

    const int b    = blockIdx.x;
    const int lane = threadIdx.x;        // 0..63
    const int hlen = hlens[b];
    const int lb   = ys_lens[b];
    const int Sb   = 2 * lb + 1;
    const float* pb = probs + (size_t)b * T_DIM * V_DIM;
    const int*  yrow = ys_pad + b * L_DIM;

    // labels for this lane's 4 odd states (8l+1,3,5,7 -> labels 4l..4l+3)
    const int y0 = yrow[4 * lane + 0];
    const int y1 = yrow[4 * lane + 1];
    const int y2 = yrow[4 * lane + 2];
    const int y3 = yrow[4 * lane + 3];
    const int ym1 = (lane > 0) ? yrow[4 * lane - 1] : -1;

    // skip-transition flags (labels are 1..4, never blank, per setup)
    const bool sk0 = (lane > 0) && (y0 != ym1);
    const bool sk1 = (y1 != y0);
    const bool sk2 = (y2 != y1);
    const bool sk3 = (y3 != y2);
    // symbol-select masks (V=5, labels in 1..4)
    const bool c01 = (y0 == 1), c02 = (y0 == 2), c03 = (y0 == 3);
    const bool c11 = (y1 == 1), c12 = (y1 == 2), c13 = (y1 == 3);
    const bool c21 = (y2 == 1), c22 = (y2 == 2), c23 = (y2 == 3);
    const bool c31 = (y3 == 1), c32 = (y3 == 2), c33 = (y3 == 3);

    // valid-state masks; states >= Sb never feed readout (deps go upward
    // only) and are zeroed at every renorm so they cannot overflow.
    bool vmask[9];
#pragma unroll
    for (int i = 0; i < 9; ++i) vmask[i] = (8 * lane + i) < Sb;

    double aA[9], aB[9];
#pragma unroll
    for (int i = 0; i < 9; ++i) aA[i] = 0.0;
    if (lane == 0) {
        aA[0] = (double)pb[0];        // state 0: blank at t=0
        aA[1] = (double)pb[y0];       // state 1: first label at t=0
    }
    int E = 0;   // accumulated base-2 exponent (exact)

#define STEPX(O, N, l0, l1, l2, l3, l4)                                   \
    {                                                                     \
        double p7 = __shfl_up(O[7], 1, 64);                               \
        if (lane == 0) p7 = 0.0;                                          \
        float z0f = c01 ? (l1) : (c02 ? (l2) : (c03 ? (l3) : (l4)));      \
        float z1f = c11 ? (l1) : (c12 ? (l2) : (c13 ? (l3) : (l4)));      \
        float z2f = c21 ? (l1) : (c22 ? (l2) : (c23 ? (l3) : (l4)));      \
        float z3f = c31 ? (l1) : (c32 ? (l2) : (c33 ? (l3) : (l4)));      \
        double bl = (double)(l0);                                         \
        double z0 = (double)z0f, z1 = (double)z1f;                        \
        double z2 = (double)z2f, z3 = (double)z3f;                        \
        N[0] = (O[0] + p7) * bl;                                          \
        N[1] = (O[1] + O[0] + (sk0 ? p7 : 0.0)) * z0;                     \
        N[2] = (O[2] + O[1]) * bl;                                        \
        N[3] = (O[3] + O[2] + (sk1 ? O[1] : 0.0)) * z1;                   \
        N[4] = (O[4] + O[3]) * bl;                                        \
        N[5] = (O[5] + O[4] + (sk2 ? O[3] : 0.0)) * z2;                   \
        N[6] = (O[6] + O[5]) * bl;                                        \
        N[7] = (O[7] + O[6] + (sk3 ? O[5] : 0.0)) * z3;                   \
        N[8] = (O[8] + O[7]) * bl;                                        \
    }

#define LOADPAIR(buf, tt)                                                 \
    {                                                                     \
        int ta_ = (tt) < hlen ? (tt) : (hlen - 1);                        \
        int tb_ = (tt) + 1 < hlen ? (tt) + 1 : (hlen - 1);                \
        const float* qa_ = pb + (size_t)ta_ * V_DIM;                      \
        const float* qb_ = pb + (size_t)tb_ * V_DIM;                      \
        buf[0] = qa_[0]; buf[1] = qa_[1]; buf[2] = qa_[2];                \
        buf[3] = qa_[3]; buf[4] = qa_[4];                                 \
        buf[5] = qb_[0]; buf[6] = qb_[1]; buf[7] = qb_[2];                \
        buf[8] = qb_[3]; buf[9] = qb_[4];                                 \
    }

#define RENORM()                                                          \
    {                                                                     \
        double m_ = 0.0;                                                  \
        _Pragma("unroll")                                                 \
        for (int i_ = 0; i_ < 9; ++i_)                                    \
            m_ = fmax(m_, vmask[i_] ? aA[i_] : 0.0);                      \
        m_ = fmax(m_, __shfl_xor(m_, 1, 64));                             \
        m_ = fmax(m_, __shfl_xor(m_, 2, 64));                             \
        m_ = fmax(m_, __shfl_xor(m_, 4, 64));                             \
        m_ = fmax(m_, __shfl_xor(m_, 8, 64));                             \
        m_ = fmax(m_, __shfl_xor(m_, 16, 64));                            \
        m_ = fmax(m_, __shfl_xor(m_, 32, 64));                            \
        int e_ = 0;                                                       \
        (void)frexp(m_, &e_);                                             \
        double sc_ = ldexp(1.0, -e_);                                     \
        _Pragma("unroll")                                                 \
        for (int i_ = 0; i_ < 9; ++i_)                                    \
            aA[i_] = vmask[i_] ? aA[i_] * sc_ : 0.0;                      \
        E += e_;                                                          \
    }

    const int NS = hlen - 1;        // steps t = 1 .. hlen-1
    const int npair = NS >> 1;
    int p = 0;
    int t = 1;
    float lpA[10], lpB[10];
    LOADPAIR(lpA, 1);

    for (; p + 2 <= npair; p += 2) {
        LOADPAIR(lpB, t + 2);
        STEPX(aA, aB, lpA[0], lpA[1], lpA[2], lpA[3], lpA[4]);
        STEPX(aB, aA, lpA[5], lpA[6], lpA[7], lpA[8], lpA[9]);
        LOADPAIR(lpA, t + 4);
        STEPX(aA, aB, lpB[0], lpB[1], lpB[2], lpB[3], lpB[4]);
        STEPX(aB, aA, lpB[5], lpB[6], lpB[7], lpB[8], lpB[9]);
        t += 4;
        if (p & 2) RENORM();        // every 8 steps (exact pow2, E exact)
    }

    int r = NS - (t - 1);           // 0..3 steps remain; lpA holds (t, t+1)
    if (r >= 2) {
        STEPX(aA, aB, lpA[0], lpA[1], lpA[2], lpA[3], lpA[4]);
        STEPX(aB, aA, lpA[5], lpA[6], lpA[7], lpA[8], lpA[9]);
        t += 2; r -= 2;
    }
    if (r == 1) {
        LOADPAIR(lpB, t);
        STEPX(aA, aB, lpB[0], lpB[1], lpB[2], lpB[3], lpB[4]);
#pragma unroll
        for (int i = 0; i < 9; ++i) aA[i] = aB[i];
    }

    // readout
#pragma unroll
    for (int i = 0; i < 8; ++i) s_alpha[8 * lane + i] = aA[i];
    if (lane == 63) s_alpha[512] = aA[8];
    __syncthreads();
    if (lane == 0) {
        int i1 = 2 * lb - 1;
        double s = s_alpha[i1] + s_alpha[i1 + 1];
        double nlld = -(log(s) + (double)E * LN2D);
        float nll = (float)nlld;
        if (!(nll < 1e8f)) nll = 0.f;   // zero_infinity (covers inf/nan)
        nll_out[b] = nll;
    }
#undef STEPX
#undef LOADPAIR
#undef RENORM
}

// Kernel 3: deterministic reduction of 32 per-sample NLLs -> loss.
__global__ __launch_bounds__(64) void k_finalize(
    const float* __restrict__ nll, float* __restrict__ out)
{
    int tid = threadIdx.x;
    float v = (tid < B_DIM) ? nll[tid] : 0.f;
#pragma unroll
    for (int off = 32; off; off >>= 1) v += __shfl_down(v, off, 64);
    if (tid == 0) out[0] = v / (float)B_DIM;
}

extern "C" void kernel_launch(void* const* d_in, const int* in_sizes, int n_in,
                              void* d_out, int out_size, void* d_ws, size_t ws_size,
                              hipStream_t stream) {
    const float* hs      = (const float*)d_in[0];
    const float* W       = (const float*)d_in[1];
    const float* bias    = (const float*)d_in[2];
    const int*   hlens   = (const int*)d_in[3];
    const int*   ys_pad  = (const int*)d_in[4];
    const int*   ys_lens = (const int*)d_in[5];

    float* out   = (float*)d_out;
    float* logp  = out + 1;                                      // (B,T,V) log-softmax
    float* probs = out + 1 + (size_t)B_DIM * T_DIM * V_DIM;      // (B,T,V) softmax
    float* nll   = (float*)d_ws;                                 // 32 floats

    hipLaunchKernelGGL(k_logits_softmax, dim3(B_DIM * T_DIM / 256), dim3(256), 0, stream,
                       hs, W, bias, logp, probs);
    hipLaunchKernelGGL(k_ctc, dim3(B_DIM), dim3(64), 0, stream,
                       probs, ys_pad, hlens, ys_lens, nll);
    hipLaunchKernelGGL(k_finalize, dim3(1), dim3(64), 0, stream, nll, out);
}

// Round 4
// 228.391 us; speedup vs baseline: 8.3645x; 2.1571x over previous
//
#include <hip/hip_runtime.h>
#include <math.h>

#define B_DIM 32
#define T_DIM 2048
#define D_DIM 512
#define V_DIM 5
#define L_DIM 256
#define LN2D 0.6931471805599453

typedef const float __attribute__((address_space(1)))* gas_fp;
typedef float __attribute__((address_space(3)))* las_fp;

// Kernel 1: logits = hs @ W + b, log_softmax over V, probs. Thread-per-row.
__global__ __launch_bounds__(256) void k_logits_softmax(
    const float* __restrict__ hs, const float* __restrict__ W,
    const float* __restrict__ bias, float* __restrict__ logp,
    float* __restrict__ probs)
{
    int r = blockIdx.x * blockDim.x + threadIdx.x;   // row in [0, B*T)
    const float* x = hs + (size_t)r * D_DIM;

    float acc[V_DIM];
#pragma unroll
    for (int v = 0; v < V_DIM; ++v) acc[v] = bias[v];

    for (int k = 0; k < D_DIM; k += 8) {
        float4 xa = *reinterpret_cast<const float4*>(x + k);
        float4 xb = *reinterpret_cast<const float4*>(x + k + 4);
        const float xs[8] = {xa.x, xa.y, xa.z, xa.w, xb.x, xb.y, xb.z, xb.w};
#pragma unroll
        for (int j = 0; j < 8; ++j) {
#pragma unroll
            for (int v = 0; v < V_DIM; ++v)
                acc[v] = fmaf(xs[j], W[(k + j) * V_DIM + v], acc[v]);
        }
    }

    float m = fmaxf(fmaxf(fmaxf(acc[0], acc[1]), fmaxf(acc[2], acc[3])), acc[4]);
    float e[V_DIM];
    float s = 0.f;
#pragma unroll
    for (int v = 0; v < V_DIM; ++v) { e[v] = __expf(acc[v] - m); s += e[v]; }
    float lse = m + __logf(s);
    float inv = 1.f / s;

    size_t base = (size_t)r * V_DIM;
#pragma unroll
    for (int v = 0; v < V_DIM; ++v) {
        logp[base + v]  = acc[v] - lse;
        probs[base + v] = e[v] * inv;
    }
}

// Kernel 2: CTC forward scan, linear-prob f32 with PER-LANE block floating
// point (lane-local exponent E, renorm every 4 steps). One wave per sample,
// 8 states/lane (+1 ghost) in registers. Probs staged to LDS once via
// global_load_lds; per-step symbol probs via per-lane ds_read (y's constant
// per lane). Cross-lane term rescaled by 2^(E_prev - E) via v_ldexp_f32.
// Per-lane renorm avoids round-2's failure (global-renorm put on-track
// states 2^-350 below the pinned max, under f32 range); adjacent-lane E
// deltas stay ~30-60 bits. Empty lanes adopt upstream E each renorm (1
// lane / 4 steps = mass propagation speed of 2 states/step).
__global__ __launch_bounds__(64) void k_ctc(
    const float* __restrict__ probs, const int* __restrict__ ys_pad,
    const int* __restrict__ hlens, const int* __restrict__ ys_lens,
    float* __restrict__ nll_out)
{
    __shared__ float s_probs[(T_DIM + 8) * V_DIM];   // +8 rows: prefetch overrun pad
    __shared__ float s_alpha[513];
    __shared__ int   s_E[65];

    const int b    = blockIdx.x;
    const int lane = threadIdx.x;        // 0..63
    const int hlen = hlens[b];
    const int lb   = ys_lens[b];
    const int Sb   = 2 * lb + 1;
    const float* pb = probs + (size_t)b * T_DIM * V_DIM;
    const int*  yrow = ys_pad + b * L_DIM;

    // ---- stage all T*V probs for this sample into LDS (40 KB) ----
    // size=4 (probs region is 4B-misaligned vs 16B); 160 issues, 1 drain.
    for (int i = 0; i < (T_DIM * V_DIM) / 64; ++i) {
        __builtin_amdgcn_global_load_lds((gas_fp)(pb + i * 64 + lane),
                                         (las_fp)(&s_probs[i * 64]), 4, 0, 0);
    }
    asm volatile("s_waitcnt vmcnt(0)" ::: "memory");

    // labels for this lane's 4 odd states (8l+{1,3,5,7} -> labels 4l..4l+3)
    const int y0 = yrow[4 * lane + 0];
    const int y1 = yrow[4 * lane + 1];
    const int y2 = yrow[4 * lane + 2];
    const int y3 = yrow[4 * lane + 3];
    const int ym1 = (lane > 0) ? yrow[4 * lane - 1] : -1;

    // skip flags as 0/1 floats (labels never blank per setup)
    const float sk0f = ((lane > 0) && (y0 != ym1)) ? 1.f : 0.f;
    const float sk1f = (y1 != y0) ? 1.f : 0.f;
    const float sk2f = (y2 != y1) ? 1.f : 0.f;
    const float sk3f = (y3 != y2) ? 1.f : 0.f;

    // valid-state masks; invalid states zeroed at every renorm
    bool vmask[9];
#pragma unroll
    for (int i = 0; i < 9; ++i) vmask[i] = (8 * lane + i) < Sb;

    float aA[9], aB[9];
#pragma unroll
    for (int i = 0; i < 9; ++i) aA[i] = 0.f;
    if (lane == 0) {
        aA[0] = s_probs[0];          // state 0: blank at t=0
        aA[1] = s_probs[y0];         // state 1: first label at t=0
    }
    int E = 0;        // lane-local base-2 exponent (true = rel * 2^E)
    int delta = 0;    // E_{lane-1} - E_lane, refreshed each renorm

    // per-lane LDS read pointers, advanced +20 dwords per 4-step block
    const float* p_bl = s_probs + V_DIM;          // blank col, row t=1
    const float* p_y0 = s_probs + V_DIM + y0;
    const float* p_y1 = s_probs + V_DIM + y1;
    const float* p_y2 = s_probs + V_DIM + y2;
    const float* p_y3 = s_probs + V_DIM + y3;

#define LOADQ(dst)                                                        \
    {                                                                     \
        _Pragma("unroll")                                                 \
        for (int s_ = 0; s_ < 4; ++s_) {                                  \
            dst[s_ * 5 + 0] = p_bl[s_ * 5];                               \
            dst[s_ * 5 + 1] = p_y0[s_ * 5];                               \
            dst[s_ * 5 + 2] = p_y1[s_ * 5];                               \
            dst[s_ * 5 + 3] = p_y2[s_ * 5];                               \
            dst[s_ * 5 + 4] = p_y3[s_ * 5];                               \
        }                                                                 \
        p_bl += 20; p_y0 += 20; p_y1 += 20; p_y2 += 20; p_y3 += 20;       \
    }

#define STEPX(O, N, L, s_)                                                \
    {                                                                     \
        float p7 = __shfl_up(O[7], 1, 64);                                \
        p7 = ldexpf(p7, delta);                                           \
        if (lane == 0) p7 = 0.f;                                          \
        const float bl_ = L[(s_) * 5 + 0];                                \
        N[0] = (O[0] + p7) * bl_;                                         \
        N[1] = fmaf(sk0f, p7,   O[1] + O[0]) * L[(s_) * 5 + 1];           \
        N[2] = (O[2] + O[1]) * bl_;                                       \
        N[3] = fmaf(sk1f, O[1], O[3] + O[2]) * L[(s_) * 5 + 2];           \
        N[4] = (O[4] + O[3]) * bl_;                                       \
        N[5] = fmaf(sk2f, O[3], O[5] + O[4]) * L[(s_) * 5 + 3];           \
        N[6] = (O[6] + O[5]) * bl_;                                       \
        N[7] = fmaf(sk3f, O[5], O[7] + O[6]) * L[(s_) * 5 + 4];           \
        N[8] = (O[8] + O[7]) * bl_;                                       \
    }

#define STEP4(L)                                                          \
    STEPX(aA, aB, L, 0); STEPX(aB, aA, L, 1);                             \
    STEPX(aA, aB, L, 2); STEPX(aB, aA, L, 3);

#define RENORM()                                                          \
    {                                                                     \
        int Eold_prev = __shfl_up(E, 1, 64);                              \
        float m_ = 0.f;                                                   \
        _Pragma("unroll")                                                 \
        for (int i_ = 0; i_ < 9; ++i_)                                    \
            m_ = fmaxf(m_, vmask[i_] ? aA[i_] : 0.f);                     \
        int e_ = 0;                                                       \
        (void)frexpf(m_, &e_);          /* e_=0 when m_=0 */              \
        float sc_ = ldexpf(1.f, -e_);   /* =1 when e_=0 */                \
        _Pragma("unroll")                                                 \
        for (int i_ = 0; i_ < 9; ++i_)                                    \
            aA[i_] = vmask[i_] ? aA[i_] * sc_ : 0.f;                      \
        bool has_ = (m_ > 0.f);                                           \
        E = has_ ? (E + e_) : ((lane > 0) ? Eold_prev : E);               \
        int Enew_prev = __shfl_up(E, 1, 64);                              \
        delta = (lane == 0) ? 0 : (Enew_prev - E);                        \
    }

    const int NS = hlen - 1;       // steps t = 1..NS
    const int nfull = NS >> 2;     // full 4-step blocks
    float lpA[20], lpB[20];
    LOADQ(lpA);                    // rows 1..4

    int blk = 0;
    for (; blk + 2 <= nfull; blk += 2) {
        LOADQ(lpB);                // prefetch next block
        STEP4(lpA);
        RENORM();
        LOADQ(lpA);                // prefetch block after
        STEP4(lpB);
        RENORM();
    }
    if (blk < nfull) {             // one leftover full block, data in lpA
        STEP4(lpA);
        RENORM();
    }
    // tail steps (0..3): t = 4*nfull+1 .. NS
    for (int tt = 4 * nfull + 1; tt <= NS; ++tt) {
        const float* r_ = s_probs + tt * V_DIM;
        float lt[5] = { r_[0], r_[y0], r_[y1], r_[y2], r_[y3] };
        STEPX(aA, aB, lt, 0);
#pragma unroll
        for (int i = 0; i < 9; ++i) aA[i] = aB[i];
    }

    // ---- readout ----
#pragma unroll
    for (int i = 0; i < 8; ++i) s_alpha[8 * lane + i] = aA[i];
    s_E[lane] = E;
    if (lane == 63) { s_alpha[512] = aA[8]; s_E[64] = E; }
    __syncthreads();
    if (lane == 0) {
        int i1 = 2 * lb - 1;
        float a1 = s_alpha[i1], a2 = s_alpha[i1 + 1];
        int E1 = s_E[i1 >> 3], E2 = s_E[(i1 + 1) >> 3];
        double s = (double)a1 + ldexp((double)a2, E2 - E1);
        double nlld = -(log(s) + (double)E1 * LN2D);
        float nll = (float)nlld;
        if (!(nll < 1e8f)) nll = 0.f;   // zero_infinity (covers inf/nan)
        nll_out[b] = nll;
    }
#undef STEPX
#undef STEP4
#undef LOADQ
#undef RENORM
}

// Kernel 3: deterministic reduction of 32 per-sample NLLs -> loss.
__global__ __launch_bounds__(64) void k_finalize(
    const float* __restrict__ nll, float* __restrict__ out)
{
    int tid = threadIdx.x;
    float v = (tid < B_DIM) ? nll[tid] : 0.f;
#pragma unroll
    for (int off = 32; off; off >>= 1) v += __shfl_down(v, off, 64);
    if (tid == 0) out[0] = v / (float)B_DIM;
}

extern "C" void kernel_launch(void* const* d_in, const int* in_sizes, int n_in,
                              void* d_out, int out_size, void* d_ws, size_t ws_size,
                              hipStream_t stream) {
    const float* hs      = (const float*)d_in[0];
    const float* W       = (const float*)d_in[1];
    const float* bias    = (const float*)d_in[2];
    const int*   hlens   = (const int*)d_in[3];
    const int*   ys_pad  = (const int*)d_in[4];
    const int*   ys_lens = (const int*)d_in[5];

    float* out   = (float*)d_out;
    float* logp  = out + 1;                                      // (B,T,V) log-softmax
    float* probs = out + 1 + (size_t)B_DIM * T_DIM * V_DIM;      // (B,T,V) softmax
    float* nll   = (float*)d_ws;                                 // 32 floats

    hipLaunchKernelGGL(k_logits_softmax, dim3(B_DIM * T_DIM / 256), dim3(256), 0, stream,
                       hs, W, bias, logp, probs);
    hipLaunchKernelGGL(k_ctc, dim3(B_DIM), dim3(64), 0, stream,
                       probs, ys_pad, hlens, ys_lens, nll);
    hipLaunchKernelGGL(k_finalize, dim3(1), dim3(64), 0, stream, nll, out);
}